// Round 11
// baseline (77.291 us; speedup 1.0000x reference)
//
#include <hip/hip_runtime.h>

// Mixture-of-64-tiny-experts, fp32.
// R10: discriminating experiment. Identical math/structure to R9 (subnet-pair
// v2f packing, 1 sample/thread, 8 waves/SIMD) but weights staged in LDS
// (12.3KB/block, cooperative load, wave-uniform ds_read broadcast in loop)
// instead of per-iteration s_load chains that exceed the SGPR file (112 SGPR
// ~= ceiling -> no double-buffering -> per-iter lgkmcnt stall).
// __launch_bounds__(256,8) pins 8 waves/SIMD.

#define NSUB 64
#define L2E  1.4426950408889634f   // log2(e)
#define L2E2 2.8853900817779268f   // 2*log2(e)

typedef float v2f __attribute__((ext_vector_type(2)));

__device__ __forceinline__ v2f pk_fma(v2f a, v2f b, v2f c) {
    return __builtin_elementwise_fma(a, b, c);
}
__device__ __forceinline__ v2f sp(float s) { return v2f{s, s}; }

// packed tanhshrink(a) = (a-1) + 2*rcp(exp2(2L*a)+1)
__device__ __forceinline__ v2f tanhshrink_v(v2f a) {
    v2f s = a * L2E2;
    v2f e;
    e.x = __builtin_amdgcn_exp2f(s.x);
    e.y = __builtin_amdgcn_exp2f(s.y);
    v2f ep = e + 1.0f;
    v2f r;
    r.x = __builtin_amdgcn_rcpf(ep.x);
    r.y = __builtin_amdgcn_rcpf(ep.y);
    return pk_fma(sp(2.0f), r, a - 1.0f);
}

// packed tanh from pre-scaled input s = 2*log2e*raw
__device__ __forceinline__ v2f tanh_scaled_v(v2f s) {
    v2f e;
    e.x = __builtin_amdgcn_exp2f(s.x);
    e.y = __builtin_amdgcn_exp2f(s.y);
    v2f ep = e + 1.0f;
    v2f r;
    r.x = __builtin_amdgcn_rcpf(ep.x);
    r.y = __builtin_amdgcn_rcpf(ep.y);
    return pk_fma(sp(-2.0f), r, sp(1.0f));
}

// scalar tanhshrink for the once-per-thread gating net
__device__ __forceinline__ float tanhshrink_s(float a) {
    float e = __builtin_amdgcn_exp2f(a * L2E2);
    float r = __builtin_amdgcn_rcpf(e + 1.0f);
    return fmaf(2.0f, r, a - 1.0f);
}

// Pack per subnet-PAIR p (p, p+32), 96 floats = 48 v2f slots:
// [0:24) W1 pairs (j*6+i) | [24:28) b1 | [28:36) W2*2L (o*4+j) | [36:38) b2*2L
// [38:44) Gw2*L | [44] Gb2*L | [45:48) pad
__global__ void pack_kernel(const float* __restrict__ W1, const float* __restrict__ b1,
                            const float* __restrict__ W2, const float* __restrict__ b2,
                            const float* __restrict__ Gw2, const float* __restrict__ Gb2,
                            float* __restrict__ ws)
{
    int p = threadIdx.x;
    if (p >= 32) return;
    int sa = p, sb = p + 32;
    float* f = ws + p * 96;
    for (int i = 0; i < 24; ++i) { f[2*i]   = W1[sa*24+i];        f[2*i+1]   = W1[sb*24+i]; }
    for (int i = 0; i < 4;  ++i) { f[48+2*i] = b1[sa*4+i];        f[48+2*i+1] = b1[sb*4+i]; }
    for (int i = 0; i < 8;  ++i) { f[56+2*i] = W2[sa*8+i]*L2E2;   f[56+2*i+1] = W2[sb*8+i]*L2E2; }
    for (int i = 0; i < 2;  ++i) { f[72+2*i] = b2[sa*2+i]*L2E2;   f[72+2*i+1] = b2[sb*2+i]*L2E2; }
    for (int i = 0; i < 6;  ++i) { f[76+2*i] = Gw2[sa*6+i]*L2E;   f[76+2*i+1] = Gw2[sb*6+i]*L2E; }
    f[88] = Gb2[sa]*L2E; f[89] = Gb2[sb]*L2E;
    f[90] = 0.f; f[91] = 0.f; f[92] = 0.f; f[93] = 0.f; f[94] = 0.f; f[95] = 0.f;
}

__global__ __launch_bounds__(256, 8) void moe_kernel(
    const float* __restrict__ x,
    const float* __restrict__ wpack,
    const float* __restrict__ Gw1, const float* __restrict__ Gb1,
    float* __restrict__ out)
{
    // ---- stage the 12.3KB weight pack into LDS (cooperative) ----
    __shared__ float lw[32 * 96];          // 12288 B
    {
        const float4* src4 = (const float4*)wpack;
        float4* dst4 = (float4*)lw;
        int tid = threadIdx.x;
#pragma unroll
        for (int k = 0; k < 3; ++k)
            dst4[tid * 3 + k] = src4[tid * 3 + k];
    }

    long t = blockIdx.x * blockDim.x + threadIdx.x;

    // one sample: 6 floats, 24B stride -> three float2 loads
    const float2* xv = (const float2*)(x + t * 6);
    float2 p0 = xv[0];
    float2 p1 = xv[1];
    float2 p2 = xv[2];
    float xs[6] = {p0.x, p0.y, p1.x, p1.y, p2.x, p2.y};

    // ---- gating hidden (scalar, once per thread; overlaps staging) ----
    float ga[6];
#pragma unroll
    for (int j = 0; j < 6; ++j) {
        float s = Gb1[j];
#pragma unroll
        for (int i = 0; i < 6; ++i)
            s = fmaf(Gw1[j * 6 + i], xs[i], s);
        ga[j] = tanhshrink_s(s);
    }

    v2f xa[6], gab[6];
#pragma unroll
    for (int i = 0; i < 6; ++i) xa[i] = sp(xs[i]);
#pragma unroll
    for (int j = 0; j < 6; ++j) gab[j] = sp(ga[j]);

    __syncthreads();

    // ---- 32 iterations; v2f halves cover subnets p and p+32 ----
    v2f acc0 = sp(0.f), acc1 = sp(0.f), accE = sp(0.f);

#pragma unroll 2
    for (int p = 0; p < 32; ++p) {
        const v2f* f2 = (const v2f*)(lw + p * 96);   // LDS, wave-uniform addr

        v2f h[4];
#pragma unroll
        for (int j = 0; j < 4; ++j) {
            v2f s = pk_fma(f2[j * 6 + 0], xa[0], f2[24 + j]);
#pragma unroll
            for (int i = 1; i < 6; ++i)
                s = pk_fma(f2[j * 6 + i], xa[i], s);
            h[j] = tanhshrink_v(s);
        }

        v2f o0 = pk_fma(f2[28], h[0], f2[36]);   // W2,b2 pre-scaled by 2*log2e
        o0 = pk_fma(f2[29], h[1], o0);
        o0 = pk_fma(f2[30], h[2], o0);
        o0 = pk_fma(f2[31], h[3], o0);
        o0 = tanh_scaled_v(o0);

        v2f o1 = pk_fma(f2[32], h[0], f2[37]);
        o1 = pk_fma(f2[33], h[1], o1);
        o1 = pk_fma(f2[34], h[2], o1);
        o1 = pk_fma(f2[35], h[3], o1);
        o1 = tanh_scaled_v(o1);

        v2f la = pk_fma(f2[38], gab[0], f2[44]); // Gw2,Gb2 pre-scaled by log2e
        la = pk_fma(f2[39], gab[1], la);
        la = pk_fma(f2[40], gab[2], la);
        la = pk_fma(f2[41], gab[3], la);
        la = pk_fma(f2[42], gab[4], la);
        la = pk_fma(f2[43], gab[5], la);
        v2f ea;
        ea.x = __builtin_amdgcn_exp2f(la.x);
        ea.y = __builtin_amdgcn_exp2f(la.y);

        accE = accE + ea;
        acc0 = pk_fma(ea, o0, acc0);
        acc1 = pk_fma(ea, o1, acc1);
    }

    // cross-half reduction (subnets 0-31 in .x, 32-63 in .y)
    float E  = accE.x + accE.y;
    float r  = __builtin_amdgcn_rcpf(E);
    float u0 = (acc0.x + acc0.y) * r;
    float u1 = (acc1.x + acc1.y) * r;
    float2 res; res.x = u0; res.y = u1;
    ((float2*)&out[t * 2])[0] = res;
}

extern "C" void kernel_launch(void* const* d_in, const int* in_sizes, int n_in,
                              void* d_out, int out_size, void* d_ws, size_t ws_size,
                              hipStream_t stream) {
    const float* x   = (const float*)d_in[0];
    const float* W1  = (const float*)d_in[1];
    const float* b1  = (const float*)d_in[2];
    const float* W2  = (const float*)d_in[3];
    const float* b2  = (const float*)d_in[4];
    const float* Gw1 = (const float*)d_in[5];
    const float* Gb1 = (const float*)d_in[6];
    const float* Gw2 = (const float*)d_in[7];
    const float* Gb2 = (const float*)d_in[8];
    float* out = (float*)d_out;
    float* ws  = (float*)d_ws;   // 32*96*4 = 12 KB

    pack_kernel<<<1, 64, 0, stream>>>(W1, b1, W2, b2, Gw2, Gb2, ws);

    const int threads = 256;
    const int blocks = 524288 / threads;  // 2048, 1 sample/thread
    moe_kernel<<<blocks, threads, 0, stream>>>(x, ws, Gw1, Gb1, out);
}

// Round 12
// 68.856 us; speedup vs baseline: 1.1225x; 1.1225x over previous
//
#include <hip/hip_runtime.h>

// Mixture-of-64-tiny-experts, fp32.
// R11: R9 structure (subnet-pair v2f packing, 1 sample/thread, 8 waves/SIMD,
// s_load weights). Single change: activation reciprocals (12 v_rcp/iter,
// 16cyc each, issue-blocking) -> packed Newton-Raphson: magic seed
// 0x7EF312AC + one pk Newton step (r*(2-d*r)). Trans/iter 26 -> 14.
// Model B (confirmed R4/R9/R10): pk=4cyc, scalar=2cyc, trans=16cyc, all
// serialized on the issue port -> predicted 664->572 cyc/iter, ~60us.

#define NSUB 64
#define L2E  1.4426950408889634f   // log2(e)
#define L2E2 2.8853900817779268f   // 2*log2(e)

typedef float v2f __attribute__((ext_vector_type(2)));

__device__ __forceinline__ v2f pk_fma(v2f a, v2f b, v2f c) {
    return __builtin_elementwise_fma(a, b, c);
}
__device__ __forceinline__ v2f sp(float s) { return v2f{s, s}; }

// packed reciprocal: magic seed (optimal for 1 NR) + one packed Newton step.
// rel err <= ~8.8e-4. d > 1 always here (d = exp2(..)+1), no edge cases.
__device__ __forceinline__ v2f pk_rcp_nr(v2f d) {
    v2f r;
    r.x = __int_as_float(0x7EF312AC - __float_as_int(d.x));
    r.y = __int_as_float(0x7EF312AC - __float_as_int(d.y));
    v2f c = sp(2.0f) - d * r;   // pk_mul + pk_sub (pure float, no fneg)
    return r * c;               // pk_mul
}

// packed tanhshrink(a) = (a-1) + 2*rcp(exp2(2L*a)+1)
__device__ __forceinline__ v2f tanhshrink_v(v2f a) {
    v2f s = a * L2E2;
    v2f e;
    e.x = __builtin_amdgcn_exp2f(s.x);
    e.y = __builtin_amdgcn_exp2f(s.y);
    v2f r = pk_rcp_nr(e + 1.0f);
    return pk_fma(sp(2.0f), r, a - 1.0f);
}

// packed tanh from pre-scaled input s = 2*log2e*raw: 1 - 2*rcp(exp2(s)+1)
__device__ __forceinline__ v2f tanh_scaled_v(v2f s) {
    v2f e;
    e.x = __builtin_amdgcn_exp2f(s.x);
    e.y = __builtin_amdgcn_exp2f(s.y);
    v2f r = pk_rcp_nr(e + 1.0f);
    return pk_fma(sp(-2.0f), r, sp(1.0f));
}

// scalar tanhshrink for the once-per-thread gating net (hw rcp: negligible)
__device__ __forceinline__ float tanhshrink_s(float a) {
    float e = __builtin_amdgcn_exp2f(a * L2E2);
    float r = __builtin_amdgcn_rcpf(e + 1.0f);
    return fmaf(2.0f, r, a - 1.0f);
}

// Pack per subnet-PAIR p (p, p+32), 96 floats = 48 v2f slots:
// [0:24) W1 pairs (j*6+i) | [24:28) b1 | [28:36) W2*2L (o*4+j) | [36:38) b2*2L
// [38:44) Gw2*L | [44] Gb2*L | [45:48) pad
__global__ void pack_kernel(const float* __restrict__ W1, const float* __restrict__ b1,
                            const float* __restrict__ W2, const float* __restrict__ b2,
                            const float* __restrict__ Gw2, const float* __restrict__ Gb2,
                            float* __restrict__ ws)
{
    int p = threadIdx.x;
    if (p >= 32) return;
    int sa = p, sb = p + 32;
    float* f = ws + p * 96;
    for (int i = 0; i < 24; ++i) { f[2*i]   = W1[sa*24+i];        f[2*i+1]   = W1[sb*24+i]; }
    for (int i = 0; i < 4;  ++i) { f[48+2*i] = b1[sa*4+i];        f[48+2*i+1] = b1[sb*4+i]; }
    for (int i = 0; i < 8;  ++i) { f[56+2*i] = W2[sa*8+i]*L2E2;   f[56+2*i+1] = W2[sb*8+i]*L2E2; }
    for (int i = 0; i < 2;  ++i) { f[72+2*i] = b2[sa*2+i]*L2E2;   f[72+2*i+1] = b2[sb*2+i]*L2E2; }
    for (int i = 0; i < 6;  ++i) { f[76+2*i] = Gw2[sa*6+i]*L2E;   f[76+2*i+1] = Gw2[sb*6+i]*L2E; }
    f[88] = Gb2[sa]*L2E; f[89] = Gb2[sb]*L2E;
    f[90] = 0.f; f[91] = 0.f; f[92] = 0.f; f[93] = 0.f; f[94] = 0.f; f[95] = 0.f;
}

__global__ __launch_bounds__(256) void moe_kernel(
    const float* __restrict__ x,
    const float* __restrict__ wpack,
    const float* __restrict__ Gw1, const float* __restrict__ Gb1,
    float* __restrict__ out)
{
    long t = blockIdx.x * blockDim.x + threadIdx.x;

    // one sample: 6 floats, 24B stride -> three float2 loads
    const float2* xv = (const float2*)(x + t * 6);
    float2 p0 = xv[0];
    float2 p1 = xv[1];
    float2 p2 = xv[2];
    float xs[6] = {p0.x, p0.y, p1.x, p1.y, p2.x, p2.y};

    // ---- gating hidden (scalar, once per thread) ----
    float ga[6];
#pragma unroll
    for (int j = 0; j < 6; ++j) {
        float s = Gb1[j];
#pragma unroll
        for (int i = 0; i < 6; ++i)
            s = fmaf(Gw1[j * 6 + i], xs[i], s);
        ga[j] = tanhshrink_s(s);
    }

    // broadcast sample values / gating hidden into both pk halves
    v2f xa[6], gab[6];
#pragma unroll
    for (int i = 0; i < 6; ++i) xa[i] = sp(xs[i]);
#pragma unroll
    for (int j = 0; j < 6; ++j) gab[j] = sp(ga[j]);

    // ---- 32 iterations; v2f halves cover subnets p and p+32 ----
    v2f acc0 = sp(0.f), acc1 = sp(0.f), accE = sp(0.f);

#pragma unroll 2
    for (int p = 0; p < 32; ++p) {
        const v2f* f2 = (const v2f*)(wpack + p * 96);   // 48 subnet-pair slots

        v2f h[4];
#pragma unroll
        for (int j = 0; j < 4; ++j) {
            v2f s = pk_fma(f2[j * 6 + 0], xa[0], f2[24 + j]);
#pragma unroll
            for (int i = 1; i < 6; ++i)
                s = pk_fma(f2[j * 6 + i], xa[i], s);
            h[j] = tanhshrink_v(s);
        }

        v2f o0 = pk_fma(f2[28], h[0], f2[36]);   // W2,b2 pre-scaled by 2*log2e
        o0 = pk_fma(f2[29], h[1], o0);
        o0 = pk_fma(f2[30], h[2], o0);
        o0 = pk_fma(f2[31], h[3], o0);
        o0 = tanh_scaled_v(o0);

        v2f o1 = pk_fma(f2[32], h[0], f2[37]);
        o1 = pk_fma(f2[33], h[1], o1);
        o1 = pk_fma(f2[34], h[2], o1);
        o1 = pk_fma(f2[35], h[3], o1);
        o1 = tanh_scaled_v(o1);

        v2f la = pk_fma(f2[38], gab[0], f2[44]); // Gw2,Gb2 pre-scaled by log2e
        la = pk_fma(f2[39], gab[1], la);
        la = pk_fma(f2[40], gab[2], la);
        la = pk_fma(f2[41], gab[3], la);
        la = pk_fma(f2[42], gab[4], la);
        la = pk_fma(f2[43], gab[5], la);
        v2f ea;
        ea.x = __builtin_amdgcn_exp2f(la.x);
        ea.y = __builtin_amdgcn_exp2f(la.y);

        accE = accE + ea;
        acc0 = pk_fma(ea, o0, acc0);
        acc1 = pk_fma(ea, o1, acc1);
    }

    // cross-half reduction (subnets 0-31 in .x, 32-63 in .y); hw rcp is fine
    float E  = accE.x + accE.y;
    float r  = __builtin_amdgcn_rcpf(E);
    float u0 = (acc0.x + acc0.y) * r;
    float u1 = (acc1.x + acc1.y) * r;
    float2 res; res.x = u0; res.y = u1;
    ((float2*)&out[t * 2])[0] = res;
}

extern "C" void kernel_launch(void* const* d_in, const int* in_sizes, int n_in,
                              void* d_out, int out_size, void* d_ws, size_t ws_size,
                              hipStream_t stream) {
    const float* x   = (const float*)d_in[0];
    const float* W1  = (const float*)d_in[1];
    const float* b1  = (const float*)d_in[2];
    const float* W2  = (const float*)d_in[3];
    const float* b2  = (const float*)d_in[4];
    const float* Gw1 = (const float*)d_in[5];
    const float* Gb1 = (const float*)d_in[6];
    const float* Gw2 = (const float*)d_in[7];
    const float* Gb2 = (const float*)d_in[8];
    float* out = (float*)d_out;
    float* ws  = (float*)d_ws;   // 32*96*4 = 12 KB

    pack_kernel<<<1, 64, 0, stream>>>(W1, b1, W2, b2, Gw2, Gb2, ws);

    const int threads = 256;
    const int blocks = 524288 / threads;  // 2048, 1 sample/thread
    moe_kernel<<<blocks, threads, 0, stream>>>(x, ws, Gw1, Gb1, out);
}

// Round 13
// 68.313 us; speedup vs baseline: 1.1314x; 1.0079x over previous
//
#include <hip/hip_runtime.h>

// Mixture-of-64-tiny-experts, fp32.
// R12: fetch-amortization experiment. Evidence (R4==R9==R11==72us despite
// wildly different VALU/trans mixes; R2 at 2x fetch-ratio = 90us; R10 LDS
// path = 80us) says the kernel is bound on wave-uniform weight-fetch
// throughput (s_load/K$), ~250cyc/iter. Fix: 2 samples per thread with the
// SAME subnet-pair weight fetch -> bytes-per-work halved. Two independent
// per-sample chains also double in-thread ILP (occupancy drops to 4
// waves/SIMD; R4 proved that's fine). Math identical to R11 (NR rcp).

#define NSUB 64
#define L2E  1.4426950408889634f   // log2(e)
#define L2E2 2.8853900817779268f   // 2*log2(e)

typedef float v2f __attribute__((ext_vector_type(2)));

__device__ __forceinline__ v2f pk_fma(v2f a, v2f b, v2f c) {
    return __builtin_elementwise_fma(a, b, c);
}
__device__ __forceinline__ v2f sp(float s) { return v2f{s, s}; }

// packed reciprocal: magic seed + one packed Newton step. rel err ~8.8e-4.
__device__ __forceinline__ v2f pk_rcp_nr(v2f d) {
    v2f r;
    r.x = __int_as_float(0x7EF312AC - __float_as_int(d.x));
    r.y = __int_as_float(0x7EF312AC - __float_as_int(d.y));
    v2f c = sp(2.0f) - d * r;
    return r * c;
}

// packed tanhshrink(a) = (a-1) + 2*rcp(exp2(2L*a)+1)
__device__ __forceinline__ v2f tanhshrink_v(v2f a) {
    v2f s = a * L2E2;
    v2f e;
    e.x = __builtin_amdgcn_exp2f(s.x);
    e.y = __builtin_amdgcn_exp2f(s.y);
    v2f r = pk_rcp_nr(e + 1.0f);
    return pk_fma(sp(2.0f), r, a - 1.0f);
}

// packed tanh from pre-scaled input s = 2*log2e*raw: 1 - 2*rcp(exp2(s)+1)
__device__ __forceinline__ v2f tanh_scaled_v(v2f s) {
    v2f e;
    e.x = __builtin_amdgcn_exp2f(s.x);
    e.y = __builtin_amdgcn_exp2f(s.y);
    v2f r = pk_rcp_nr(e + 1.0f);
    return pk_fma(sp(-2.0f), r, sp(1.0f));
}

// scalar tanhshrink for the once-per-sample gating net
__device__ __forceinline__ float tanhshrink_s(float a) {
    float e = __builtin_amdgcn_exp2f(a * L2E2);
    float r = __builtin_amdgcn_rcpf(e + 1.0f);
    return fmaf(2.0f, r, a - 1.0f);
}

// Pack per subnet-PAIR p (p, p+32), 96 floats = 48 v2f slots:
// [0:24) W1 pairs (j*6+i) | [24:28) b1 | [28:36) W2*2L (o*4+j) | [36:38) b2*2L
// [38:44) Gw2*L | [44] Gb2*L | [45:48) pad
__global__ void pack_kernel(const float* __restrict__ W1, const float* __restrict__ b1,
                            const float* __restrict__ W2, const float* __restrict__ b2,
                            const float* __restrict__ Gw2, const float* __restrict__ Gb2,
                            float* __restrict__ ws)
{
    int p = threadIdx.x;
    if (p >= 32) return;
    int sa = p, sb = p + 32;
    float* f = ws + p * 96;
    for (int i = 0; i < 24; ++i) { f[2*i]   = W1[sa*24+i];        f[2*i+1]   = W1[sb*24+i]; }
    for (int i = 0; i < 4;  ++i) { f[48+2*i] = b1[sa*4+i];        f[48+2*i+1] = b1[sb*4+i]; }
    for (int i = 0; i < 8;  ++i) { f[56+2*i] = W2[sa*8+i]*L2E2;   f[56+2*i+1] = W2[sb*8+i]*L2E2; }
    for (int i = 0; i < 2;  ++i) { f[72+2*i] = b2[sa*2+i]*L2E2;   f[72+2*i+1] = b2[sb*2+i]*L2E2; }
    for (int i = 0; i < 6;  ++i) { f[76+2*i] = Gw2[sa*6+i]*L2E;   f[76+2*i+1] = Gw2[sb*6+i]*L2E; }
    f[88] = Gb2[sa]*L2E; f[89] = Gb2[sb]*L2E;
    f[90] = 0.f; f[91] = 0.f; f[92] = 0.f; f[93] = 0.f; f[94] = 0.f; f[95] = 0.f;
}

__global__ __launch_bounds__(256) void moe_kernel(
    const float* __restrict__ x,
    const float* __restrict__ wpack,
    const float* __restrict__ Gw1, const float* __restrict__ Gb1,
    float* __restrict__ out)
{
    long t = blockIdx.x * blockDim.x + threadIdx.x;

    // two samples per thread: 12 floats = 3 x float4 (48B stride, aligned)
    const float4* xv = (const float4*)(x + t * 12);
    float4 q0 = xv[0];
    float4 q1 = xv[1];
    float4 q2 = xv[2];
    float xsA[6] = {q0.x, q0.y, q0.z, q0.w, q1.x, q1.y};
    float xsB[6] = {q1.z, q1.w, q2.x, q2.y, q2.z, q2.w};

    // ---- gating hidden per sample (scalar) ----
    float gaA[6], gaB[6];
#pragma unroll
    for (int j = 0; j < 6; ++j) {
        float sA = Gb1[j], sB = sA;
#pragma unroll
        for (int i = 0; i < 6; ++i) {
            float w = Gw1[j * 6 + i];
            sA = fmaf(w, xsA[i], sA);
            sB = fmaf(w, xsB[i], sB);
        }
        gaA[j] = tanhshrink_s(sA);
        gaB[j] = tanhshrink_s(sB);
    }

    // broadcast into pk halves (halves differ by SUBNET, so sample value is
    // duplicated across halves)
    v2f xaA[6], xaB[6], gbA[6], gbB[6];
#pragma unroll
    for (int i = 0; i < 6; ++i) { xaA[i] = sp(xsA[i]); xaB[i] = sp(xsB[i]); }
#pragma unroll
    for (int j = 0; j < 6; ++j) { gbA[j] = sp(gaA[j]); gbB[j] = sp(gaB[j]); }

    // ---- 32 iterations; v2f halves cover subnets p and p+32; 2 samples ----
    v2f acc0A = sp(0.f), acc1A = sp(0.f), accEA = sp(0.f);
    v2f acc0B = sp(0.f), acc1B = sp(0.f), accEB = sp(0.f);

#pragma unroll 2
    for (int p = 0; p < 32; ++p) {
        const v2f* f2 = (const v2f*)(wpack + p * 96);   // 48 subnet-pair slots

        v2f hA[4], hB[4];
#pragma unroll
        for (int j = 0; j < 4; ++j) {
            v2f w0 = f2[j * 6 + 0];
            v2f bb = f2[24 + j];
            v2f sA = pk_fma(w0, xaA[0], bb);
            v2f sB = pk_fma(w0, xaB[0], bb);
#pragma unroll
            for (int i = 1; i < 6; ++i) {
                v2f w = f2[j * 6 + i];
                sA = pk_fma(w, xaA[i], sA);
                sB = pk_fma(w, xaB[i], sB);
            }
            hA[j] = tanhshrink_v(sA);
            hB[j] = tanhshrink_v(sB);
        }

        v2f o0A, o0B, o1A, o1B;
        {
            v2f w28 = f2[28], w29 = f2[29], w30 = f2[30], w31 = f2[31], b0 = f2[36];
            o0A = pk_fma(w28, hA[0], b0);  o0B = pk_fma(w28, hB[0], b0);
            o0A = pk_fma(w29, hA[1], o0A); o0B = pk_fma(w29, hB[1], o0B);
            o0A = pk_fma(w30, hA[2], o0A); o0B = pk_fma(w30, hB[2], o0B);
            o0A = pk_fma(w31, hA[3], o0A); o0B = pk_fma(w31, hB[3], o0B);
            o0A = tanh_scaled_v(o0A);      o0B = tanh_scaled_v(o0B);
        }
        {
            v2f w32 = f2[32], w33 = f2[33], w34 = f2[34], w35 = f2[35], b1v = f2[37];
            o1A = pk_fma(w32, hA[0], b1v); o1B = pk_fma(w32, hB[0], b1v);
            o1A = pk_fma(w33, hA[1], o1A); o1B = pk_fma(w33, hB[1], o1B);
            o1A = pk_fma(w34, hA[2], o1A); o1B = pk_fma(w34, hB[2], o1B);
            o1A = pk_fma(w35, hA[3], o1A); o1B = pk_fma(w35, hB[3], o1B);
            o1A = tanh_scaled_v(o1A);      o1B = tanh_scaled_v(o1B);
        }

        v2f laA, laB;
        {
            v2f g0 = f2[38], g1 = f2[39], g2 = f2[40], g3 = f2[41], g4 = f2[42],
                g5 = f2[43], gb = f2[44];
            laA = pk_fma(g0, gbA[0], gb);  laB = pk_fma(g0, gbB[0], gb);
            laA = pk_fma(g1, gbA[1], laA); laB = pk_fma(g1, gbB[1], laB);
            laA = pk_fma(g2, gbA[2], laA); laB = pk_fma(g2, gbB[2], laB);
            laA = pk_fma(g3, gbA[3], laA); laB = pk_fma(g3, gbB[3], laB);
            laA = pk_fma(g4, gbA[4], laA); laB = pk_fma(g4, gbB[4], laB);
            laA = pk_fma(g5, gbA[5], laA); laB = pk_fma(g5, gbB[5], laB);
        }
        v2f eA, eB;
        eA.x = __builtin_amdgcn_exp2f(laA.x);
        eA.y = __builtin_amdgcn_exp2f(laA.y);
        eB.x = __builtin_amdgcn_exp2f(laB.x);
        eB.y = __builtin_amdgcn_exp2f(laB.y);

        accEA = accEA + eA;            accEB = accEB + eB;
        acc0A = pk_fma(eA, o0A, acc0A); acc0B = pk_fma(eB, o0B, acc0B);
        acc1A = pk_fma(eA, o1A, acc1A); acc1B = pk_fma(eB, o1B, acc1B);
    }

    // cross-half reductions (subnets 0-31 in .x, 32-63 in .y)
    float EA = accEA.x + accEA.y;
    float EB = accEB.x + accEB.y;
    float rA = __builtin_amdgcn_rcpf(EA);
    float rB = __builtin_amdgcn_rcpf(EB);
    float4 res;
    res.x = (acc0A.x + acc0A.y) * rA;
    res.y = (acc1A.x + acc1A.y) * rA;
    res.z = (acc0B.x + acc0B.y) * rB;
    res.w = (acc1B.x + acc1B.y) * rB;
    ((float4*)&out[t * 4])[0] = res;
}

extern "C" void kernel_launch(void* const* d_in, const int* in_sizes, int n_in,
                              void* d_out, int out_size, void* d_ws, size_t ws_size,
                              hipStream_t stream) {
    const float* x   = (const float*)d_in[0];
    const float* W1  = (const float*)d_in[1];
    const float* b1  = (const float*)d_in[2];
    const float* W2  = (const float*)d_in[3];
    const float* b2  = (const float*)d_in[4];
    const float* Gw1 = (const float*)d_in[5];
    const float* Gb1 = (const float*)d_in[6];
    const float* Gw2 = (const float*)d_in[7];
    const float* Gb2 = (const float*)d_in[8];
    float* out = (float*)d_out;
    float* ws  = (float*)d_ws;   // 32*96*4 = 12 KB

    pack_kernel<<<1, 64, 0, stream>>>(W1, b1, W2, b2, Gw2, Gb2, ws);

    // 2 samples/thread -> 262144 threads -> 1024 blocks
    const int threads = 256;
    const int blocks = (524288 / 2) / threads;  // 1024
    moe_kernel<<<blocks, threads, 0, stream>>>(x, ws, Gw1, Gb1, out);
}